// Round 1
// baseline (72237.390 us; speedup 1.0000x reference)
//
#include <hip/hip_runtime.h>

// GRU persistent-kernel implementation for MI355X.
// T=32768 sequential steps; weight_hh register-resident across 32 WGs;
// h broadcast per step via tagged 8B words (value|step) at agent scope,
// double-buffered by step parity. igates GEMM fused, prefetched 1 step ahead.

#define T_STEPS 32768
#define INSZ    256
#define HSZ     512
#define NWG     32      // participating workgroups
#define SWG     16      // h outputs owned per WG  (NWG*SWG == HSZ)
#define TPB     256     // threads per block
// group: 16 threads per owned h-output ("super-row" of 3x512 hh + 3x256 ih weights)

typedef unsigned long long u64;
typedef unsigned int u32;

__device__ __forceinline__ float grp_reduce16(float v) {
  v += __shfl_xor(v, 1);
  v += __shfl_xor(v, 2);
  v += __shfl_xor(v, 4);
  v += __shfl_xor(v, 8);
  return v;
}

// index padding for h in LDS: +4 floats per 32 (keeps float4 alignment,
// breaks the stride-32 bank alias: chunk base l*36 -> bank-group rotates)
__device__ __forceinline__ int hpad(int k) { return k + 4 * (k >> 5); }

__global__ void init_comm(u64* __restrict__ comm, const float* __restrict__ h0) {
  int j = threadIdx.x;
  if (j < HSZ) {
    u32 bits = __float_as_uint(h0[j]);
    comm[j]       = (u64)bits;                  // buf0: tag 0 + h0 value
    comm[HSZ + j] = 0xFFFFFFFF00000000ull;      // buf1: invalid tag
  }
}

__launch_bounds__(TPB, 1)
__global__ void gru_persistent(const float* __restrict__ input,
                               const float* __restrict__ w_ih,
                               const float* __restrict__ w_hh,
                               const float* __restrict__ bias,
                               const float* __restrict__ bias_n,
                               u64* __restrict__ comm,
                               float* __restrict__ out)
{
  const int tid = threadIdx.x;
  const int wg  = blockIdx.x;
  const int g   = tid >> 4;          // 0..15  owned-row within WG
  const int l   = tid & 15;          // 0..15  lane within group
  const int j   = wg * SWG + g;      // owned global h index

  // ---- load weights into registers (one-time) ----
  float whh[3][32];   // rows j, j+512, j+1024 ; k-range [l*32, l*32+32)
  float wih[3][16];   // same rows of w_ih     ; k-range [l*16, l*16+16)
  #pragma unroll
  for (int q = 0; q < 3; ++q) {
    const float* rp = w_hh + (size_t)(j + 512 * q) * HSZ + l * 32;
    #pragma unroll
    for (int c = 0; c < 8; ++c) {
      float4 v = *(const float4*)(rp + c * 4);
      whh[q][c*4+0] = v.x; whh[q][c*4+1] = v.y;
      whh[q][c*4+2] = v.z; whh[q][c*4+3] = v.w;
    }
    const float* rp2 = w_ih + (size_t)(j + 512 * q) * INSZ + l * 16;
    #pragma unroll
    for (int c = 0; c < 4; ++c) {
      float4 v = *(const float4*)(rp2 + c * 4);
      wih[q][c*4+0] = v.x; wih[q][c*4+1] = v.y;
      wih[q][c*4+2] = v.z; wih[q][c*4+3] = v.w;
    }
  }
  const float b_r = bias[j], b_z = bias[j + 512], b_n = bias[j + 1024];
  const float bn2 = bias_n[j];

  __shared__ float h_lds[HSZ + 4 * (HSZ >> 5)];

  // ---- igates for step 0 ----
  float ig0, ig1, ig2;
  {
    const float* ip = input + l * 16;
    float a0 = 0.f, a1 = 0.f, a2 = 0.f;
    #pragma unroll
    for (int c = 0; c < 4; ++c) {
      float4 v = *(const float4*)(ip + c * 4);
      float xv[4] = {v.x, v.y, v.z, v.w};
      #pragma unroll
      for (int u = 0; u < 4; ++u) {
        a0 += wih[0][c*4+u] * xv[u];
        a1 += wih[1][c*4+u] * xv[u];
        a2 += wih[2][c*4+u] * xv[u];
      }
    }
    ig0 = grp_reduce16(a0); ig1 = grp_reduce16(a1); ig2 = grp_reduce16(a2);
  }

  for (int t = 0; t < T_STEPS; ++t) {
    u64* buf = comm + (size_t)(t & 1) * HSZ;
    const u32 tt = (u32)t;

    // ---- poll h_t (each thread owns words tid and tid+256) ----
    u64 w0 = 0, w1 = 0;
    bool d0 = false, d1 = false;
    do {
      if (!d0) { w0 = __hip_atomic_load(buf + tid,       __ATOMIC_RELAXED, __HIP_MEMORY_SCOPE_AGENT); d0 = ((u32)(w0 >> 32)) == tt; }
      if (!d1) { w1 = __hip_atomic_load(buf + tid + 256, __ATOMIC_RELAXED, __HIP_MEMORY_SCOPE_AGENT); d1 = ((u32)(w1 >> 32)) == tt; }
    } while (!(d0 && d1));
    h_lds[hpad(tid)]       = __uint_as_float((u32)w0);
    h_lds[hpad(tid + 256)] = __uint_as_float((u32)w1);
    __syncthreads();

    // ---- issue next input-row loads early (latency hidden under matvec) ----
    const int tn = (t + 1 < T_STEPS) ? (t + 1) : (T_STEPS - 1);
    const float* ipn = input + (size_t)tn * INSZ + l * 16;
    float4 nv0 = *(const float4*)(ipn + 0);
    float4 nv1 = *(const float4*)(ipn + 4);
    float4 nv2 = *(const float4*)(ipn + 8);
    float4 nv3 = *(const float4*)(ipn + 12);

    // ---- hh matvec (critical path) ----
    float hr = 0.f, hz = 0.f, hn = 0.f;
    const float* hp = &h_lds[l * 36];   // hpad(l*32)
    #pragma unroll
    for (int c = 0; c < 8; ++c) {
      float4 hv = *(const float4*)(hp + c * 4);
      float hvv[4] = {hv.x, hv.y, hv.z, hv.w};
      #pragma unroll
      for (int u = 0; u < 4; ++u) {
        hr += whh[0][c*4+u] * hvv[u];
        hz += whh[1][c*4+u] * hvv[u];
        hn += whh[2][c*4+u] * hvv[u];
      }
    }
    hr = grp_reduce16(hr); hz = grp_reduce16(hz); hn = grp_reduce16(hn);

    const float ir  = ig0 + b_r, iz = ig1 + b_z, inn = ig2 + b_n;
    const float reset = 1.0f / (1.0f + __expf(-(ir + hr)));
    const float upd   = 1.0f / (1.0f + __expf(-(iz + hz)));
    const float hold  = h_lds[hpad(j)];
    const float newv  = tanhf(inn + reset * (hn + bn2));
    const float hnew  = newv + upd * (hold - newv);

    if (l == 0) {
      u64 w = ((u64)(u32)(t + 1) << 32) | (u64)__float_as_uint(hnew);
      u64* nbuf = comm + (size_t)((t + 1) & 1) * HSZ;
      __hip_atomic_store(nbuf + j, w, __ATOMIC_RELAXED, __HIP_MEMORY_SCOPE_AGENT);
      if (j == 0) out[t] = hnew;
    }

    // ---- igates for step t+1 (off critical path) ----
    {
      float a0 = 0.f, a1 = 0.f, a2 = 0.f;
      float xv[16] = {nv0.x, nv0.y, nv0.z, nv0.w,  nv1.x, nv1.y, nv1.z, nv1.w,
                      nv2.x, nv2.y, nv2.z, nv2.w,  nv3.x, nv3.y, nv3.z, nv3.w};
      #pragma unroll
      for (int u = 0; u < 16; ++u) {
        a0 += wih[0][u] * xv[u];
        a1 += wih[1][u] * xv[u];
        a2 += wih[2][u] * xv[u];
      }
      ig0 = grp_reduce16(a0); ig1 = grp_reduce16(a1); ig2 = grp_reduce16(a2);
    }
    __syncthreads();   // protect h_lds before next iteration's fill
  }
}

extern "C" void kernel_launch(void* const* d_in, const int* in_sizes, int n_in,
                              void* d_out, int out_size, void* d_ws, size_t ws_size,
                              hipStream_t stream) {
  const float* input  = (const float*)d_in[0];
  const float* h0     = (const float*)d_in[1];
  const float* w_ih   = (const float*)d_in[2];
  const float* w_hh   = (const float*)d_in[3];
  const float* bias   = (const float*)d_in[4];
  const float* bias_n = (const float*)d_in[5];
  float* out = (float*)d_out;
  u64* comm  = (u64*)d_ws;   // 2 * 512 * 8B = 8 KB

  hipLaunchKernelGGL(init_comm, dim3(1), dim3(HSZ), 0, stream, comm, h0);
  hipLaunchKernelGGL(gru_persistent, dim3(NWG), dim3(TPB), 0, stream,
                     input, w_ih, w_hh, bias, bias_n, comm, out);
}